// Round 11
// baseline (42060.767 us; speedup 1.0000x reference)
//
#include <hip/hip_runtime.h>
#include <hip/hip_fp16.h>

#define HID   512
#define EMB   256
#define VOCAB 64
#define BS    64
#define SLEN  128
#define LLEN  1024
#define G4    2048
#define NB    512          // 4 groups x 128 blocks, 2 blocks/CU
#define NT    512
#define NW    8            // waves per block
#define NG    4            // independent batch groups
#define GB    128          // blocks per group
#define BSG   16           // batch rows per group
#define ASTR2 18           // f32 row stride of unpacked tile
#define ASZ2  (256 * ASTR2)

typedef unsigned u32x4 __attribute__((ext_vector_type(4)));

// ---------------------------------------------------------------------------
// MALL-coherent (cache-bypass) access helpers — proven R5-R10 protocol
__device__ __forceinline__ u32x4 vldq(const unsigned* p) {
    return *reinterpret_cast<const volatile u32x4*>(p);
}
__device__ __forceinline__ float vld1(const float* p) {
    return *reinterpret_cast<const volatile float*>(p);
}
__device__ __forceinline__ void vst1(float* p, float v) {
    *reinterpret_cast<volatile float*>(p) = v;
}
__device__ __forceinline__ void vstu(unsigned* p, unsigned v) {
    *reinterpret_cast<volatile unsigned*>(p) = v;
}
__device__ __forceinline__ unsigned packh2(float x, float y) {
    __half2 h = __floats2half2_rn(x, y);
    return *reinterpret_cast<unsigned*>(&h);
}

// ---------------------------------------------------------------------------
// LDS. As = double-buffered f32 tile [2][256][18]; red = [wave][20 rows][16b+pad]
struct SCell { float As[2 * ASZ2]; float red[NW][20][18]; };
struct SAttn { float u_s[512]; float w_s[32]; float msh[4];
               float accs[16][34]; unsigned enc[32 * 261]; };
struct SLog  { float red[8 * 65]; };
union SMem { SCell c; SAttn a; SLog lg; };

// ---------------------------------------------------------------------------
// per-group grid barrier: flat slot array (no RMW). 128 slots per group,
// wave0 polls its group's slots (2 coalesced loads/lane + __all).
__device__ __forceinline__ void gridbar(unsigned* bar, int g, int gbid, unsigned nb)
{
    __syncthreads();
    const int t = threadIdx.x;
    if (t < 64) {
        unsigned* slots = bar + g * 256;
        if (t == 0)
            __hip_atomic_store(slots + gbid, nb, __ATOMIC_RELAXED,
                               __HIP_MEMORY_SCOPE_AGENT);
        for (;;) {
            bool ok = true;
#pragma unroll
            for (int i = 0; i < 2; ++i) {
                unsigned v = __hip_atomic_load(slots + i * 64 + t, __ATOMIC_RELAXED,
                                               __HIP_MEMORY_SCOPE_AGENT);
                ok &= (v >= nb);
            }
            if (__all((int)ok)) break;
            __builtin_amdgcn_s_sleep(1);
        }
    }
    __syncthreads();
}

// ---------------------------------------------------------------------------
// one-time kernels
__global__ __launch_bounds__(256)
void k_embed16T(const int* __restrict__ y, const float* __restrict__ emb,
                __half* __restrict__ xemb16)   // [t][g][e][16] f16
{
    int i = blockIdx.x * 256 + threadIdx.x;
    int ts  = i >> 14;
    int g   = (i >> 12) & 3;
    int e   = (i >> 4) & 255;
    int b16 = i & 15;
    int b = g * 16 + b16;
    xemb16[i] = __float2half(emb[y[b * SLEN + ts] * EMB + e]);
}

__global__ __launch_bounds__(256)
void k_cast(const float* __restrict__ src, __half* __restrict__ dst, int n4)
{
    int i = blockIdx.x * 256 + threadIdx.x;
    int stride = gridDim.x * 256;
    for (; i < n4; i += stride) {
        float4 v = reinterpret_cast<const float4*>(src)[i];
        reinterpret_cast<__half2*>(dst)[2 * i]     = __floats2half2_rn(v.x, v.y);
        reinterpret_cast<__half2*>(dst)[2 * i + 1] = __floats2half2_rn(v.z, v.w);
    }
}

__global__ __launch_bounds__(256)
void k_pmat(const float* __restrict__ Whw, const float* __restrict__ Wsw,
            const float* __restrict__ Wsb, float* __restrict__ P,
            float* __restrict__ p0)
{
    const int i = blockIdx.x;
    const int t = threadIdx.x;
    float a0 = 0.f, a1 = 0.f, ap = 0.f;
    for (int h = 0; h < HID; ++h) {
        float whi = Whw[h * HID + i];
        a0 += whi * Wsw[h * HID + t];
        a1 += whi * Wsw[h * HID + t + 256];
        ap += whi * Wsb[h];
    }
    P[i * HID + t]       = a0;
    P[i * HID + t + 256] = a1;
    if (t == 0) p0[i] = ap;
}

// fold ctx=Whw@chat+Whb into consumers (exact algebra, proven R7-R10)
__global__ __launch_bounds__(256)
void k_fold(const float* __restrict__ aWih, const float* __restrict__ W1,
            const float* __restrict__ Whw, const float* __restrict__ Whb,
            const float* __restrict__ abih, const float* __restrict__ b1,
            float* __restrict__ Wp, float* __restrict__ W1bp,
            float* __restrict__ bihEff, float* __restrict__ b1eff)
{
    const int r = blockIdx.x;
    const int t = threadIdx.x;
    __shared__ float ssrc[512];
    const float* src;
    float* dst;
    if (r < G4) { src = aWih + (size_t)r * (EMB + HID) + EMB; dst = Wp + (size_t)r * HID; }
    else        { src = W1 + (size_t)(r - G4) * (2 * HID) + HID; dst = W1bp + (size_t)(r - G4) * HID; }
    ssrc[t]       = src[t];
    ssrc[t + 256] = src[t + 256];
    __syncthreads();
    float a0 = 0.f, a1 = 0.f;
    for (int h = 0; h < HID; ++h) {
        const float s = ssrc[h];
        a0 += s * Whw[h * HID + t];
        a1 += s * Whw[h * HID + t + 256];
    }
    dst[t]       = a0;
    dst[t + 256] = a1;
    if (t == 0) {
        float bb = 0.f;
        for (int h = 0; h < HID; ++h) bb += ssrc[h] * Whb[h];
        if (r < G4) bihEff[r] = abih[r] + bb;
        else        b1eff[r - G4] = b1[r - G4] + bb;
    }
}

// ---------------------------------------------------------------------------
// staged group-blocked f16 scan. A points at a [512+][16] f16 block (already
// group-offset). Tiles of 256 k: 512 threads x 16B fully-coalesced load,
// unpack once to f32 LDS [256][18] (write ~2-3way, read conflict-free).
// Per lane: r = lane>>4 selects its h-row; w[] are per-lane row base ptrs.
template<int NTILES, int NR, bool VOL>
__device__ __forceinline__ void segScanT(float* As, const __half* A,
    const float* const* w, float* acc, int wv, int lb)
{
    const int t = threadIdx.x;
    const unsigned* ga = reinterpret_cast<const unsigned*>(A)
                       + (size_t)(t >> 1) * 8 + (t & 1) * 4;
    const int kRow = t >> 1;
    const int c0   = (t & 1) * 8;
    u32x4 Ra, Rb;
    Ra = VOL ? vldq(ga) : *reinterpret_cast<const u32x4*>(ga);
    __syncthreads();                     // handoff: prior users of As done
#pragma unroll
    for (int j = 0; j < NTILES; ++j) {
        {
            float2* dst2 = reinterpret_cast<float2*>(As + (j & 1) * ASZ2 + kRow * ASTR2 + c0);
            const u32x4 R = (j & 1) ? Rb : Ra;
#pragma unroll
            for (int h = 0; h < 4; ++h) {
                unsigned uw = R[h];
                dst2[h] = __half22float2(*reinterpret_cast<const __half2*>(&uw));
            }
        }
        if (j + 1 < NTILES) {
            const unsigned* p = ga + (size_t)(j + 1) * 2048;
            if (j & 1) Ra = VOL ? vldq(p) : *reinterpret_cast<const u32x4*>(p);
            else       Rb = VOL ? vldq(p) : *reinterpret_cast<const u32x4*>(p);
        }
        __syncthreads();
        const float* as = As + (j & 1) * ASZ2 + (wv * 32) * ASTR2 + lb;
#pragma unroll
        for (int kk = 0; kk < 32; ++kk) {
            const float a = as[kk * ASTR2];
            const int k = j * 256 + wv * 32 + kk;
#pragma unroll
            for (int r = 0; r < NR; ++r)
                acc[r] += a * w[r][k];
        }
    }
}

// coalesced h-state pack-write: 4 rows x 16 b f16 into [g][k][16] layout
__device__ __forceinline__ void packRows(unsigned* dstU, int g, int i0,
                                         const float (&htmp)[4][16])
{
    const int t = threadIdx.x;
    if (t < 32) {
        const int row = t >> 3, pair = t & 7;
        vstu(dstU + (size_t)g * 4096 + (size_t)(i0 + row) * 8 + pair,
             packh2(htmp[row][pair * 2], htmp[row][pair * 2 + 1]));
    }
}

// ---------------------------------------------------------------------------
// phase A: attention-input LSTM cell + fused hid(t-1) finish
__device__ __forceinline__ void phaseA(SMem& sm, int g, int i0, int tstep,
    const __half* xemb16, const __half* chatT, const __half* h0rT,
    const float* __restrict__ aWih, const float* __restrict__ Wp,
    const float* __restrict__ aWhh, const float* __restrict__ W1bp,
    const float* __restrict__ bihEff, const float* __restrict__ abhh,
    float* cp, const float* hpartPriv, unsigned* h0wU, float* hid,
    float (&htmp)[4][16], int wv, int lane)
{
    const int r  = lane >> 4;
    const int lb = lane & 15;
    float acc[5] = {};
    {   // x segment (k=256)
        const float* w4[4];
#pragma unroll
        for (int q = 0; q < 4; ++q)
            w4[q] = aWih + (size_t)(q * HID + i0 + r) * (EMB + HID);
        segScanT<1, 4, false>(sm.c.As, xemb16 + (size_t)tstep * 16384 + g * 4096,
                              w4, acc, wv, lb);
    }
    {   // chat segment (folded ctx weights) + fused W1bp row
        const float* w5[5];
#pragma unroll
        for (int q = 0; q < 4; ++q)
            w5[q] = Wp + (size_t)(q * HID + i0 + r) * HID;
        w5[4] = W1bp + (size_t)(i0 + r) * HID;
        segScanT<2, 5, true>(sm.c.As, chatT + (size_t)g * 8192, w5, acc, wv, lb);
    }
    {   // recurrent h segment
        const float* w4[4];
#pragma unroll
        for (int q = 0; q < 4; ++q)
            w4[q] = aWhh + (size_t)(q * HID + i0 + r) * HID;
        segScanT<2, 4, true>(sm.c.As, h0rT + (size_t)g * 8192, w4, acc, wv, lb);
    }
#pragma unroll
    for (int q = 0; q < 4; ++q) sm.c.red[wv][q * 4 + r][lb] = acc[q];
    sm.c.red[wv][16 + r][lb] = acc[4];
    __syncthreads();
    const int t = threadIdx.x;
    if (t < 64) {
        const int b = t & 15, rr = t >> 4;
        float gs[4];
#pragma unroll
        for (int q = 0; q < 4; ++q) {
            const int row = q * HID + i0 + rr;
            float s = bihEff[row] + abhh[row];
#pragma unroll
            for (int w = 0; w < NW; ++w) s += sm.c.red[w][q * 4 + rr][b];
            gs[q] = s;
        }
        const float ig = 1.f / (1.f + __expf(-gs[0]));
        const float fg = 1.f / (1.f + __expf(-gs[1]));
        const float gg = tanhf(gs[2]);
        const float og = 1.f / (1.f + __expf(-gs[3]));
        const float c2 = fg * cp[rr * 16 + b] + ig * gg;
        cp[rr * 16 + b] = c2;
        htmp[rr][b] = og * tanhf(c2);
    } else if (t < 128) {
        const int b = t & 15, rr = (t >> 4) - 4;
        float s = hpartPriv[rr * 16 + b];
#pragma unroll
        for (int w = 0; w < NW; ++w) s += sm.c.red[w][16 + rr][b];
        vst1(hid + (size_t)(g * 16 + b) * HID + i0 + rr, fmaxf(s, 0.f));
    }
    __syncthreads();
    packRows(h0wU, g, i0, htmp);
}

// phases B, C: plain rnn LSTM cell
__device__ __forceinline__ void phaseR(SMem& sm, int g, int i0,
    const __half* inT, const __half* recT,
    const float* __restrict__ Wih, const float* __restrict__ Whh,
    const float* __restrict__ bih, const float* __restrict__ bhh,
    float* cp, unsigned* hOutU, float (&htmp)[4][16], int wv, int lane)
{
    const int r  = lane >> 4;
    const int lb = lane & 15;
    float acc[4] = {};
    {
        const float* w4[4];
#pragma unroll
        for (int q = 0; q < 4; ++q)
            w4[q] = Wih + (size_t)(q * HID + i0 + r) * HID;
        segScanT<2, 4, true>(sm.c.As, inT + (size_t)g * 8192, w4, acc, wv, lb);
    }
    {
        const float* w4[4];
#pragma unroll
        for (int q = 0; q < 4; ++q)
            w4[q] = Whh + (size_t)(q * HID + i0 + r) * HID;
        segScanT<2, 4, true>(sm.c.As, recT + (size_t)g * 8192, w4, acc, wv, lb);
    }
#pragma unroll
    for (int q = 0; q < 4; ++q) sm.c.red[wv][q * 4 + r][lb] = acc[q];
    __syncthreads();
    const int t = threadIdx.x;
    if (t < 64) {
        const int b = t & 15, rr = t >> 4;
        float gs[4];
#pragma unroll
        for (int q = 0; q < 4; ++q) {
            const int row = q * HID + i0 + rr;
            float s = bih[row] + bhh[row];
#pragma unroll
            for (int w = 0; w < NW; ++w) s += sm.c.red[w][q * 4 + rr][b];
            gs[q] = s;
        }
        const float ig = 1.f / (1.f + __expf(-gs[0]));
        const float fg = 1.f / (1.f + __expf(-gs[1]));
        const float gg = tanhf(gs[2]);
        const float og = 1.f / (1.f + __expf(-gs[3]));
        const float c2 = fg * cp[rr * 16 + b] + ig * gg;
        cp[rr * 16 + b] = c2;
        htmp[rr][b] = og * tanhf(c2);
    }
    __syncthreads();
    packRows(hOutU, g, i0, htmp);
}

// logits: per group 16 b x 8 v-groups of 8; block -> (b = gbid&15, vg = gbid>>4)
__device__ __forceinline__ void logitsPhase(SMem& sm, int g, int gbid,
    const float* hid, const float* __restrict__ W2,
    const float* __restrict__ b2, float* __restrict__ out, int tstep)
{
    const int t  = threadIdx.x;
    const int b  = gbid & 15;
    const int vg = gbid >> 4;
    const int gb = g * 16 + b;
    const int vp = t >> 6;        // 0..7
    const int kk = t & 63;        // 0..63
    float hreg[8];
    const float* hp = hid + (size_t)gb * HID + kk * 8;
#pragma unroll
    for (int k = 0; k < 8; ++k) hreg[k] = vld1(hp + k);
    const float* w = W2 + (size_t)(vg * 8 + vp) * HID + kk * 8;
    float s = 0.f;
#pragma unroll
    for (int k = 0; k < 8; ++k) s += hreg[k] * w[k];
    __syncthreads();
    sm.lg.red[vp * 65 + kk] = s;
    __syncthreads();
    if (t < 8) {
        float acc = b2[vg * 8 + t];
#pragma unroll
        for (int k = 0; k < 64; ++k) acc += sm.lg.red[t * 65 + k];
        out[((size_t)gb * SLEN + tstep) * VOCAB + vg * 8 + t] = acc;
    }
    __syncthreads();
}

// phase D: dual GEMV (u -> global f32, hpart -> LDS)
__device__ __forceinline__ void phaseD(SMem& sm, int g, int i0,
    const __half* prevT, const float* __restrict__ Pm,
    const float* __restrict__ p0v, const float* __restrict__ W1,
    const float* __restrict__ b1eff, float* u, float* hpartPriv,
    int wv, int lane)
{
    const int r  = lane >> 4;
    const int lb = lane & 15;
    float acc[2] = {};
    const float* w2[2];
    w2[0] = Pm + (size_t)(i0 + r) * HID;
    w2[1] = W1 + (size_t)(i0 + r) * (2 * HID);
    segScanT<2, 2, true>(sm.c.As, prevT + (size_t)g * 8192, w2, acc, wv, lb);
    sm.c.red[wv][r][lb]     = acc[0];
    sm.c.red[wv][4 + r][lb] = acc[1];
    __syncthreads();
    const int t = threadIdx.x;
    if (t < 128) {
        const int b = t & 15, rr = t >> 4;   // 0..7
        float s = 0.f;
#pragma unroll
        for (int w = 0; w < NW; ++w) s += sm.c.red[w][rr][b];
        if (rr < 4) vst1(u + (size_t)(g * 16 + b) * HID + i0 + rr, s + p0v[i0 + rr]);
        else        hpartPriv[(rr - 4) * 16 + b] = s + b1eff[i0 + rr - 4];
    }
}

// phase E: attention partials. group: 16 b x 8 chunks of 128 l.
__device__ __forceinline__ void phaseE(SMem& sm, int g, int gbid,
    const float* u, const __half* __restrict__ enc16,
    float* pm, float* ps, float* pv)
{
    const int t    = threadIdx.x;
    const int b    = gbid >> 3;
    const int ch   = gbid & 7;
    const int gb   = g * 16 + b;
    const int half = t >> 8;
    const int col  = t & 255;
    const int le   = t & 31;
    const int seg  = t >> 5;
    const int sq   = t & 15;
    const int sl   = (t >> 4) & 31;

    sm.a.u_s[t] = vld1(u + (size_t)gb * HID + t);
    if (t == 0) { sm.a.msh[0] = -3.0e38f; sm.a.msh[1] = 0.f; sm.a.msh[2] = 0.f; }
    float vx = 0.f, vy = 0.f;

    const uint4* src = reinterpret_cast<const uint4*>(enc16 + ((size_t)gb * LLEN + ch * 128) * HID);
    uint4 R[4];
#pragma unroll
    for (int p = 0; p < 4; ++p) R[p] = src[(size_t)sl * 64 + p * 16 + sq];
    __syncthreads();

    for (int blk = 0; blk < 4; ++blk) {
        {
            unsigned* dst = &sm.a.enc[sl * 261];
#pragma unroll
            for (int p = 0; p < 4; ++p) {
                const int c4 = (p * 16 + sq) * 4;
                dst[c4] = R[p].x; dst[c4+1] = R[p].y; dst[c4+2] = R[p].z; dst[c4+3] = R[p].w;
            }
        }
        __syncthreads();
        if (blk < 3) {
#pragma unroll
            for (int p = 0; p < 4; ++p)
                R[p] = src[((size_t)(blk + 1) * 32 + sl) * 64 + p * 16 + sq];
        }
        {   // scores: 16 segs x 32 rows, 16 half2 each
            float eacc = 0.f;
            const unsigned* er = &sm.a.enc[le * 261];
            const float* us = sm.a.u_s;
#pragma unroll
            for (int uu = 0; uu < 16; ++uu) {
                const int uo = seg * 16 + uu;
                unsigned uw = er[uo];
                float2 f2 = __half22float2(*reinterpret_cast<const __half2*>(&uw));
                eacc += us[2 * uo] * f2.x + us[2 * uo + 1] * f2.y;
            }
            sm.a.accs[seg][le] = eacc;
        }
        __syncthreads();
        if (t < 32) {
            float e = 0.f;
#pragma unroll
            for (int s2 = 0; s2 < 16; ++s2) e += sm.a.accs[s2][t];
            float bm = e;
#pragma unroll
            for (int off = 16; off > 0; off >>= 1) bm = fmaxf(bm, __shfl_xor(bm, off));
            const float m_old = sm.a.msh[0];
            const float m_new = fmaxf(m_old, bm);
            const float wl = __expf(e - m_new);
            float sw = wl;
#pragma unroll
            for (int off = 16; off > 0; off >>= 1) sw += __shfl_xor(sw, off);
            sm.a.w_s[t] = wl;
            if (t == 0) {
                const float sc = __expf(m_old - m_new);
                sm.a.msh[2] = sc;
                sm.a.msh[1] = sm.a.msh[1] * sc + sw;
                sm.a.msh[0] = m_new;
            }
        }
        __syncthreads();
        {
            const float sc = sm.a.msh[2];
            vx *= sc; vy *= sc;
#pragma unroll
            for (int ll = 0; ll < 16; ++ll) {
                const int l = half * 16 + ll;
                const float wl = sm.a.w_s[l];
                unsigned uw = sm.a.enc[l * 261 + col];
                float2 f2 = __half22float2(*reinterpret_cast<const __half2*>(&uw));
                vx += wl * f2.x; vy += wl * f2.y;
            }
        }
        __syncthreads();
    }
    if (half == 1) { sm.a.u_s[2 * col] = vx; sm.a.u_s[2 * col + 1] = vy; }
    __syncthreads();
    if (half == 0) {
        vx += sm.a.u_s[2 * col];
        vy += sm.a.u_s[2 * col + 1];
        const int pc = gb * 8 + ch;
        vst1(pv + (size_t)pc * HID + 2 * col,     vx);
        vst1(pv + (size_t)pc * HID + 2 * col + 1, vy);
        if (t == 0) { vst1(pm + pc, sm.a.msh[0]); vst1(ps + pc, sm.a.msh[1]); }
    }
}

// phase F: combine 8 chunk partials -> normalized chat, group-blocked f16
__device__ __forceinline__ void phaseF(int g, int gbid,
    const float* pm, const float* ps, const float* pv, unsigned* chatU)
{
    const int t = threadIdx.x;
    if (t < 64) {
        const int b = t & 15;
        const int j = gbid * 4 + (t >> 4);
        const int gb = g * 16 + b;
        float m[8], sd[8], pvv[8];
#pragma unroll
        for (int c = 0; c < 8; ++c) m[c]   = vld1(pm + gb * 8 + c);
#pragma unroll
        for (int c = 0; c < 8; ++c) sd[c]  = vld1(ps + gb * 8 + c);
#pragma unroll
        for (int c = 0; c < 8; ++c) pvv[c] = vld1(pv + (size_t)(gb * 8 + c) * HID + j);
        float M = m[0];
#pragma unroll
        for (int c = 1; c < 8; ++c) M = fmaxf(M, m[c]);
        float den = 0.f, num = 0.f;
#pragma unroll
        for (int c = 0; c < 8; ++c) {
            float e = __expf(m[c] - M);
            den += e * sd[c]; num += e * pvv[c];
        }
        float v = num / den;
        float vn = __shfl_down(v, 1);
        if (!(b & 1))
            vstu(chatU + (size_t)g * 4096 + (size_t)j * 8 + (b >> 1), packh2(v, vn));
    }
}

// tail: hid(S-1) = relu(hpart + W1bp@chat)
__device__ __forceinline__ void phaseT(SMem& sm, int g, int i0,
    const __half* chatT, const float* __restrict__ W1bp,
    const float* hpartPriv, float* hid, int wv, int lane)
{
    const int r  = lane >> 4;
    const int lb = lane & 15;
    float acc[1] = {};
    const float* w1[1];
    w1[0] = W1bp + (size_t)(i0 + r) * HID;
    segScanT<2, 1, true>(sm.c.As, chatT + (size_t)g * 8192, w1, acc, wv, lb);
    sm.c.red[wv][r][lb] = acc[0];
    __syncthreads();
    const int t = threadIdx.x;
    if (t < 64) {
        const int b = t & 15, rr = t >> 4;
        float s = hpartPriv[rr * 16 + b];
#pragma unroll
        for (int w = 0; w < NW; ++w) s += sm.c.red[w][rr][b];
        vst1(hid + (size_t)(g * 16 + b) * HID + i0 + rr, fmaxf(s, 0.f));
    }
}

// ---------------------------------------------------------------------------
__global__ __launch_bounds__(NT, 4)
void k_seq(const __half* __restrict__ xemb16, const __half* __restrict__ enc16,
           const float* __restrict__ aWih, const float* __restrict__ aWhh,
           const float* __restrict__ bihEff, const float* __restrict__ abhh,
           const float* __restrict__ rWih, const float* __restrict__ rWhh,
           const float* __restrict__ rbih, const float* __restrict__ rbhh,
           const float* __restrict__ Pm, const float* __restrict__ p0v,
           const float* __restrict__ W1, const float* __restrict__ b1eff,
           const float* __restrict__ Wp, const float* __restrict__ W1bp,
           const float* __restrict__ W2, const float* __restrict__ b2,
           __half* h0T, __half* hs0T, __half* hs1T, __half* chatT,
           float* u, float* hid, float* pv, float* pm, float* ps,
           float* out, unsigned* bar)
{
    __shared__ SMem sm;
    __shared__ float cPriv[3][64];
    __shared__ float hpartPriv[64];
    __shared__ float htmp[4][16];

    const int bid  = blockIdx.x;
    const int g    = bid >> 7;          // group 0..3 (blocks c, c+256 differ)
    const int gbid = bid & 127;
    const int i0   = gbid * 4;          // 4 h-rows per block
    const int t0   = threadIdx.x;
    const int wv   = __builtin_amdgcn_readfirstlane(t0 >> 6);
    const int lane = t0 & 63;
    if (t0 < 64) { cPriv[0][t0] = 0.f; cPriv[1][t0] = 0.f; cPriv[2][t0] = 0.f;
                   hpartPriv[t0] = 0.f; }
    __syncthreads();

    unsigned nb = 0;
    for (int t = 0; t < SLEN; ++t) {
        const int par = t & 1;
        const __half* h0r  = h0T  + (size_t)par * 32768;
        unsigned*     h0wU = reinterpret_cast<unsigned*>(h0T + (size_t)(par ^ 1) * 32768);
        const __half* hs0r = hs0T + (size_t)par * 32768;
        unsigned*     hs0wU = reinterpret_cast<unsigned*>(hs0T + (size_t)(par ^ 1) * 32768);
        const __half* hs0w  = hs0T + (size_t)(par ^ 1) * 32768;
        const __half* hs1r = hs1T + (size_t)par * 32768;
        unsigned*     hs1wU = reinterpret_cast<unsigned*>(hs1T + (size_t)(par ^ 1) * 32768);
        const __half* hs1w  = hs1T + (size_t)(par ^ 1) * 32768;

        phaseA(sm, g, i0, t, xemb16, chatT, h0r,
               aWih, Wp, aWhh, W1bp, bihEff, abhh,
               cPriv[0], hpartPriv, h0wU, hid, htmp, wv, lane);
        gridbar(bar, g, gbid, ++nb);
        phaseR(sm, g, i0, h0T + (size_t)(par ^ 1) * 32768, hs0r,
               rWih, rWhh, rbih, rbhh, cPriv[1], hs0wU, htmp, wv, lane);
        gridbar(bar, g, gbid, ++nb);
        phaseR(sm, g, i0, hs0w, hs1r,
               rWih + (size_t)G4 * HID, rWhh + (size_t)G4 * HID,
               rbih + G4, rbhh + G4, cPriv[2], hs1wU, htmp, wv, lane);
        gridbar(bar, g, gbid, ++nb);
        if (t > 0) logitsPhase(sm, g, gbid, hid, W2, b2, out, t - 1);
        phaseD(sm, g, i0, hs1w, Pm, p0v, W1, b1eff, u, hpartPriv, wv, lane);
        gridbar(bar, g, gbid, ++nb);
        phaseE(sm, g, gbid, u, enc16, pm, ps, pv);
        gridbar(bar, g, gbid, ++nb);
        phaseF(g, gbid, pm, ps, pv, reinterpret_cast<unsigned*>(chatT));
        gridbar(bar, g, gbid, ++nb);
    }
    phaseT(sm, g, i0, chatT, W1bp, hpartPriv, hid, wv, lane);
    gridbar(bar, g, gbid, ++nb);
    logitsPhase(sm, g, gbid, hid, W2, b2, out, SLEN - 1);
}

// ---------------------------------------------------------------------------
extern "C" void kernel_launch(void* const* d_in, const int* in_sizes, int n_in,
                              void* d_out, int out_size, void* d_ws, size_t ws_size,
                              hipStream_t stream)
{
    const int*   y    = (const int*)  d_in[0];
    const float* enc  = (const float*)d_in[1];
    const float* emb  = (const float*)d_in[2];
    const float* aWih = (const float*)d_in[3];
    const float* aWhh = (const float*)d_in[4];
    const float* abih = (const float*)d_in[5];
    const float* abhh = (const float*)d_in[6];
    const float* rWih = (const float*)d_in[7];
    const float* rWhh = (const float*)d_in[8];
    const float* rbih = (const float*)d_in[9];
    const float* rbhh = (const float*)d_in[10];
    const float* Wsw  = (const float*)d_in[11];
    const float* Wsb  = (const float*)d_in[12];
    const float* Whw  = (const float*)d_in[13];
    const float* Whb  = (const float*)d_in[14];
    const float* W1   = (const float*)d_in[15];
    const float* b1   = (const float*)d_in[16];
    const float* W2   = (const float*)d_in[17];
    const float* b2   = (const float*)d_in[18];
    float* out = (float*)d_out;

    char* base = (char*)d_ws;
    unsigned* bar = (unsigned*)base;                 base += 4096;
    // zero region (f16 group-blocked state): h0(2), hs0(2), hs1(2), chat
    __half* h0T   = (__half*)base;                   base += 2 * 65536;
    __half* hs0T  = (__half*)base;                   base += 2 * 65536;
    __half* hs1T  = (__half*)base;                   base += 2 * 65536;
    __half* chatT = (__half*)base;                   base += 65536;
    size_t zeroBytes = (size_t)(base - (char*)h0T);
    float* u      = (float*)base;                    base += 131072;
    float* hid    = (float*)base;                    base += 131072;
    float* pv     = (float*)base;                    base += 1048576;
    float* pm     = (float*)base;                    base += 2048;
    float* ps     = (float*)base;                    base += 2048;
    float* Pm     = (float*)base;                    base += 1048576;
    float* p0v    = (float*)base;                    base += 2048;
    float* Wp     = (float*)base;                    base += (size_t)G4 * HID * 4;
    float* W1bp   = (float*)base;                    base += (size_t)HID * HID * 4;
    float* bihEff = (float*)base;                    base += 8192;
    float* b1eff  = (float*)base;                    base += 2048;
    __half* xemb16 = (__half*)base;                  base += (size_t)SLEN * BS * EMB * 2;
    __half* enc16  = (__half*)base;                  base += (size_t)BS * LLEN * HID * 2;
    size_t need = (size_t)(base - (char*)d_ws);
    if (ws_size < need) return;   // loud failure (output stays zero)

    hipMemsetAsync(bar, 0, 4096, stream);
    hipMemsetAsync(h0T, 0, zeroBytes, stream);

    k_embed16T<<<(SLEN * BS * EMB) / 256, 256, 0, stream>>>(y, emb, xemb16);
    k_cast<<<4096, 256, 0, stream>>>(enc, enc16, (BS * LLEN * HID) / 4);
    k_pmat<<<HID, 256, 0, stream>>>(Whw, Wsw, Wsb, Pm, p0v);
    k_fold<<<G4 + HID, 256, 0, stream>>>(aWih, W1, Whw, Whb, abih, b1,
                                         Wp, W1bp, bihEff, b1eff);

    k_seq<<<NB, NT, 0, stream>>>(xemb16, enc16,
        aWih, aWhh, bihEff, abhh, rWih, rWhh, rbih, rbhh,
        Pm, p0v, W1, b1eff, Wp, W1bp, W2, b2,
        h0T, hs0T, hs1T, chatT, u, hid, pv, pm, ps, out, bar);
}